// Round 8
// baseline (186.716 us; speedup 1.0000x reference)
//
#include <hip/hip_runtime.h>
#include <cstddef>

#define H_IN 1024
#define W_IN 1024
#define BN_EPS 1e-5f

typedef float f32x4 __attribute__((ext_vector_type(4)));
typedef _Float16 f16x8 __attribute__((ext_vector_type(8)));

__device__ __forceinline__ void atomicMaxF(float* addr, float val) {
    if (val >= 0.0f) {
        atomicMax((int*)addr, __float_as_int(val));
    } else {
        atomicMin((unsigned int*)addr, __float_as_uint(val));
    }
}

// ---------------- stage 0: BEV init + rasterize ----------------
__global__ void k_init_bev(float* __restrict__ bev) {
    size_t i = (size_t)blockIdx.x * blockDim.x + threadIdx.x;
    int plane = (int)((i >> 20) & 1);   // H*W = 2^20
    bev[i] = plane == 0 ? -10.0f : 0.0f;
}

__global__ void k_rasterize(const float* __restrict__ pts, float* __restrict__ bev, int n) {
    int i = blockIdx.x * blockDim.x + threadIdx.x;
    if (i >= n) return;
    float fb  = pts[(size_t)i*5+0];
    float px  = pts[(size_t)i*5+1];
    float py  = pts[(size_t)i*5+2];
    float pz  = pts[(size_t)i*5+3];
    float pit = pts[(size_t)i*5+4];
    const float XS = (float)(1024.0/69.12);
    const float YS = (float)(1024.0/79.36);
    int xp = (int)(px * XS);                  // trunc toward zero, same as astype(int32)
    int yp = (int)((py + 39.68f) * YS);
    if (xp < 0 || xp >= W_IN || yp < 0 || yp >= H_IN) return;
    int b = (int)fb;
    size_t off = (size_t)(b*2) * (H_IN*(size_t)W_IN) + (size_t)yp*W_IN + xp;
    atomicMaxF(bev + off, pz);
    atomicMaxF(bev + off + (size_t)H_IN*W_IN, pit);
}

// ---------------- fused stage 1+2: conv1+BN+ReLU+pool -> conv2(grouped)+BN+ReLU+pool ----------------
// in: bev [4,2,1024,1024] f32   out: x2 [4,16,256,256] f32
// block: one 32x4 x2-tile. Phase 1: stage bev patch 2ch x 22 x 134 (f32, LDS).
// Phase 2: compute x1 tile 66x10 x 8ch into LDS (zero outside [0,512) -- conv2 zero-pad!).
// Phase 3: conv2 + pool -> x2. x1 never touches HBM (saves 67 MB vs separate kernels).
__global__ __launch_bounds__(256, 3) void k_conv12(
        const float* __restrict__ bev,
        const float* __restrict__ w0, const float* __restrict__ b0,
        const float* __restrict__ g0, const float* __restrict__ be0,
        const float* __restrict__ m0, const float* __restrict__ v0,
        const float* __restrict__ w1, const float* __restrict__ b1,
        const float* __restrict__ g1, const float* __restrict__ be1,
        const float* __restrict__ m1, const float* __restrict__ v1,
        float* __restrict__ out) {
    __shared__ float bevS[2*22*136];     // [c][22 rows][134 cols pad->136] = 23.9 KB
    __shared__ float x1S[8*10*68];       // [ch][10 rows][66 cols pad->68] = 21.8 KB
    __shared__ float w0S[144], s0S[8], t0S[8];
    __shared__ float w1S[144], s1S[16], t1S[16];
    int t = threadIdx.x;
    if (t < 144) { w0S[t] = w0[t]; w1S[t] = w1[t]; }
    if (t < 8) {
        float s = g0[t] / sqrtf(v0[t] + BN_EPS);
        s0S[t] = s; t0S[t] = (b0[t] - m0[t]) * s + be0[t];
    }
    if (t < 16) {
        float s = g1[t] / sqrtf(v1[t] + BN_EPS);
        s1S[t] = s; t1S[t] = (b1[t] - m1[t]) * s + be1[t];
    }
    int bi = blockIdx.x;                 // 2048 = 8 tx * 64 ty * 4 b
    int tx = bi & 7, ty = (bi >> 3) & 63, b = bi >> 9;
    int bx0 = 128*tx - 3, by0 = 16*ty - 3;   // bev patch origin (1024-grid)
    const float* base = bev + (size_t)b * 2 * H_IN * W_IN;

    for (int i = t; i < 2*22*134; i += 256) {
        int c = i / (22*134);
        int rem = i - c*(22*134);
        int r = rem / 134, cc = rem - r*134;
        int gy = by0 + r, gx = bx0 + cc;
        bevS[(c*22 + r)*136 + cc] =
            (gy >= 0 && gy < H_IN && gx >= 0 && gx < W_IN)
                ? base[(size_t)c*H_IN*W_IN + (size_t)gy*W_IN + gx] : 0.0f;
    }
    __syncthreads();

    // phase 2: x1 tile (512-grid rows 8ty-1.., cols 64tx-1..), 66x10, 8 ch
    for (int i = t; i < 660; i += 256) {
        int r1 = i / 66, c1 = i - r1*66;
        int gy1 = 8*ty - 1 + r1, gx1 = 64*tx - 1 + c1;
        bool valid = (gy1 >= 0 && gy1 < 512 && gx1 >= 0 && gx1 < 512);
        float p[2][4][4];
        #pragma unroll
        for (int c = 0; c < 2; c++)
            #pragma unroll
            for (int r = 0; r < 4; r++)
                #pragma unroll
                for (int cc = 0; cc < 4; cc++)
                    p[c][r][cc] = bevS[(c*22 + 2*r1 + r)*136 + 2*c1 + cc];
        #pragma unroll
        for (int oc = 0; oc < 8; oc++) {
            float mx = 0.0f;
            #pragma unroll
            for (int qy = 0; qy < 2; qy++)
                #pragma unroll
                for (int qx = 0; qx < 2; qx++) {
                    float acc = 0.0f;
                    #pragma unroll
                    for (int c = 0; c < 2; c++)
                        #pragma unroll
                        for (int kh = 0; kh < 3; kh++)
                            #pragma unroll
                            for (int kw = 0; kw < 3; kw++)
                                acc += p[c][qy+kh][qx+kw] * w0S[((oc*2+c)*3+kh)*3+kw];
                    acc = fmaxf(acc * s0S[oc] + t0S[oc], 0.0f);
                    mx = fmaxf(mx, acc);
                }
            x1S[(oc*10 + r1)*68 + c1] = valid ? mx : 0.0f;
        }
    }
    __syncthreads();

    // phase 3: 256 threads = 2 oc-halves x (32x4 pixels)
    int half = t >> 7, pix = t & 127;
    int px = pix & 31, py = pix >> 5;
    int x = 32*tx + px, y = 4*ty + py;
    float* ob = out + (size_t)b*16*256*256 + (size_t)y*256 + x;
    #pragma unroll
    for (int j = 0; j < 8; j++) {
        int oc = half*8 + j;
        int g = oc >> 1;
        float mx = 0.0f;
        #pragma unroll
        for (int qy = 0; qy < 2; qy++)
            #pragma unroll
            for (int qx = 0; qx < 2; qx++) {
                float acc = 0.0f;
                #pragma unroll
                for (int kh = 0; kh < 3; kh++)
                    #pragma unroll
                    for (int kw = 0; kw < 3; kw++)
                        acc += x1S[(g*10 + 2*py+qy+kh)*68 + 2*px+qx+kw] * w1S[(oc*3+kh)*3+kw];
                acc = fmaxf(acc * s1S[oc] + t1S[oc], 0.0f);
                mx = fmaxf(mx, acc);
            }
        ob[(size_t)oc*65536] = mx;
    }
}

// ---------------- stage 3: depthwise + pointwise + BN + ReLU -> f16 NHWC ----------------
// in: x2 [4,16,256,256] f32   out: x3h [4,256,256,32] f16
__global__ __launch_bounds__(256, 4) void k_dwpw(
                       const float* __restrict__ x2, const float* __restrict__ wdw,
                       const float* __restrict__ bdw, const float* __restrict__ wpw,
                       const float* __restrict__ bpw, const float* __restrict__ g2,
                       const float* __restrict__ be2, const float* __restrict__ m2,
                       const float* __restrict__ v2, _Float16* __restrict__ out) {
    __shared__ float patch[16*10*36];   // 23040 B
    __shared__ float wdwS[144];         // [16][3][3]
    __shared__ float bdwS[16];
    __shared__ float wpwS[512];         // [32][16]
    __shared__ float sS[32], tS[32];
    int t = threadIdx.x;
    if (t < 144) wdwS[t] = wdw[t];
    if (t < 16) bdwS[t] = bdw[t];
    for (int i = t; i < 512; i += 256) wpwS[i] = wpw[i];
    if (t < 32) {
        float s = g2[t] / sqrtf(v2[t] + BN_EPS);
        sS[t] = s;
        tS[t] = (bpw[t] - m2[t]) * s + be2[t];
    }

    int bi = blockIdx.x;                 // 1024 = 8 tx * 32 ty * 4 b
    int tx = bi & 7, ty = (bi >> 3) & 31, b = bi >> 8;
    int x0 = tx * 32, y0 = ty * 8;
    const float* base = x2 + (size_t)b * 16 * 256 * 256;

    for (int i = t; i < 16*10*34; i += 256) {
        int ic = i / 340;
        int rem = i - ic * 340;
        int r = rem / 34, c = rem - r * 34;
        int gy = y0 - 1 + r, gx = x0 - 1 + c;
        patch[(ic*10 + r)*36 + c] =
            (gy >= 0 && gy < 256 && gx >= 0 && gx < 256)
                ? base[(size_t)ic*65536 + (size_t)gy*256 + gx] : 0.0f;
    }
    __syncthreads();

    int px = t & 31, pyy = t >> 5;       // pixel within tile
    int x = x0 + px, y = y0 + pyy;

    float dv[16];
    #pragma unroll
    for (int ic = 0; ic < 16; ic++) {
        float d = bdwS[ic];
        #pragma unroll
        for (int r = 0; r < 3; r++)
            #pragma unroll
            for (int c = 0; c < 3; c++)
                d += patch[(ic*10 + pyy + r)*36 + px + c] * wdwS[ic*9 + r*3 + c];
        dv[ic] = d;
    }

    _Float16* ob = out + ((size_t)((b*256 + y)*256 + x)) * 32;
    #pragma unroll
    for (int q = 0; q < 4; q++) {
        f16x8 ov;
        #pragma unroll
        for (int j = 0; j < 8; j++) {
            int oc = q*8 + j;
            float a = 0.0f;
            #pragma unroll
            for (int ic = 0; ic < 16; ic++)
                a += dv[ic] * wpwS[oc*16+ic];
            ov[j] = (_Float16)fmaxf(a*sS[oc] + tS[oc], 0.0f);
        }
        *(f16x8*)(ob + q*8) = ov;
    }
}

// ---------------- weight prep for conv3 MFMA (9 blocks, one per tap) ----------------
// wh[khw][oc][ic] f16 = w3[oc][ic][kh][kw] * s[oc];  tv[oc] = (b3-m3)*s + be3
__global__ void k_wprep(const float* __restrict__ w3, const float* __restrict__ b3,
                        const float* __restrict__ g3, const float* __restrict__ be3,
                        const float* __restrict__ m3, const float* __restrict__ v3,
                        _Float16* __restrict__ wh, float* __restrict__ tv) {
    __shared__ float sSh[64];
    int t = threadIdx.x;
    if (t < 64) {
        float s = g3[t] / sqrtf(v3[t] + BN_EPS);
        sSh[t] = s;
        if (blockIdx.x == 0) tv[t] = (b3[t] - m3[t]) * s + be3[t];
    }
    __syncthreads();
    int khw = blockIdx.x;
    for (int i = t; i < 2048; i += 256) {
        int oc = i >> 5;                       // i = oc*32 + ic
        wh[khw*2048 + i] = (_Float16)(w3[(size_t)i*9 + khw] * sSh[oc]);
    }
}

// ---------------- stage 4: conv3 via MFMA f16 implicit GEMM + BN + ReLU + maxpool2 ----------------
// in: x3h [4,256,256,32] f16 NHWC, wh [9][64][32] f16, tv[64] f32
// out: d_out [4,64,128,128] f32
// r8: stage 10 rows ONCE per block (52.8 KB LDS), then 4 pooled-row tiles back-to-back.
// One barrier per block (was 8); y-overfetch 2.06x -> 1.29x.
__global__ __launch_bounds__(256, 2) void k_conv3m(const _Float16* __restrict__ xh,
                                                   const _Float16* __restrict__ wh,
                                                   const float* __restrict__ tv,
                                                   float* __restrict__ out) {
    __shared__ _Float16 As[10*66*40];       // rows x px x ic(pad 32->40), 52800 B
    int t = threadIdx.x;
    int lane = t & 63, w = t >> 6;
    int l15 = lane & 15, l4 = lane >> 4;
    int bi = blockIdx.x;
    int xt = bi & 3, yg = (bi >> 2) & 31, b = bi >> 7;
    int x0 = xt * 64;
    int y0 = yg * 8;                        // pre-pool row base (256-grid)

    // B fragments: weights, held in VGPRs for the whole block (36 x f16x8 = 144 VGPR)
    f16x8 Bf[9][4];
    #pragma unroll
    for (int khw = 0; khw < 9; khw++)
        #pragma unroll
        for (int g = 0; g < 4; g++)
            Bf[khw][g] = *(const f16x8*)(wh + ((khw*64 + g*16 + l15)*32 + 8*l4));

    float tvv[4];
    #pragma unroll
    for (int g = 0; g < 4; g++) tvv[g] = tv[g*16 + l15];

    // stage rows y0-1 .. y0+8 (10 rows) x 66 px x 32 ic, once
    for (int s = t; s < 660; s += 256) {
        int row = s / 66, px = s - row*66;
        int gy = y0 - 1 + row, gx = x0 - 1 + px;
        float4* dst = (float4*)&As[(row*66 + px)*40];
        if (gy >= 0 && gy < 256 && gx >= 0 && gx < 256) {
            const float4* src = (const float4*)(xh + ((size_t)((b*256 + gy)*256 + gx)) * 32);
            #pragma unroll
            for (int j = 0; j < 4; j++) dst[j] = src[j];
        } else {
            float4 z = make_float4(0.f, 0.f, 0.f, 0.f);
            #pragma unroll
            for (int j = 0; j < 4; j++) dst[j] = z;
        }
    }
    __syncthreads();

    for (int ti = 0; ti < 4; ti++) {
        int ypool = yg*4 + ti;              // pooled row 0..127
        f32x4 acc[2][4];
        #pragma unroll
        for (int f = 0; f < 2; f++)
            #pragma unroll
            for (int g = 0; g < 4; g++)
                acc[f][g] = (f32x4){0.f, 0.f, 0.f, 0.f};

        #pragma unroll
        for (int kh = 0; kh < 3; kh++)
            #pragma unroll
            for (int kw = 0; kw < 3; kw++) {
                f16x8 Af[2];
                #pragma unroll
                for (int f = 0; f < 2; f++) {
                    int row = 2*ti + f + kh;                // staged row idx
                    int px = w*16 + l15 + kw;               // staged px idx
                    Af[f] = *(const f16x8*)&As[(row*66 + px)*40 + 8*l4];
                }
                #pragma unroll
                for (int f = 0; f < 2; f++)
                    #pragma unroll
                    for (int g = 0; g < 4; g++)
                        acc[f][g] = __builtin_amdgcn_mfma_f32_16x16x32_f16(
                            Af[f], Bf[kh*3+kw][g], acc[f][g], 0, 0, 0);
            }

        // epilogue: bias + relu + 2x2 maxpool (all in-lane), store
        #pragma unroll
        for (int g = 0; g < 4; g++) {
            int oc = g*16 + l15;
            #pragma unroll
            for (int q = 0; q < 2; q++) {
                float v0 = fmaxf(fmaxf(acc[0][g][2*q]   + tvv[g], 0.f),
                                 fmaxf(acc[0][g][2*q+1] + tvv[g], 0.f));
                float v1 = fmaxf(fmaxf(acc[1][g][2*q]   + tvv[g], 0.f),
                                 fmaxf(acc[1][g][2*q+1] + tvv[g], 0.f));
                int px = x0/2 + w*8 + 2*l4 + q;
                out[(((size_t)b*64 + oc)*128 + ypool)*128 + px] = fmaxf(v0, v1);
            }
        }
    }
}

extern "C" void kernel_launch(void* const* d_in, const int* in_sizes, int n_in,
                              void* d_out, int out_size, void* d_ws, size_t ws_size,
                              hipStream_t stream) {
    const float* points = (const float*)d_in[0];
    int n = in_sizes[0] / 5;
    const float* w0  = (const float*)d_in[2];
    const float* b0  = (const float*)d_in[3];
    const float* g0  = (const float*)d_in[4];
    const float* be0 = (const float*)d_in[5];
    const float* m0  = (const float*)d_in[6];
    const float* v0  = (const float*)d_in[7];
    const float* w1  = (const float*)d_in[8];
    const float* b1  = (const float*)d_in[9];
    const float* g1  = (const float*)d_in[10];
    const float* be1 = (const float*)d_in[11];
    const float* m1  = (const float*)d_in[12];
    const float* v1  = (const float*)d_in[13];
    const float* wdw = (const float*)d_in[14];
    const float* bdw = (const float*)d_in[15];
    const float* wpw = (const float*)d_in[16];
    const float* bpw = (const float*)d_in[17];
    const float* g2  = (const float*)d_in[18];
    const float* be2 = (const float*)d_in[19];
    const float* m2  = (const float*)d_in[20];
    const float* v2  = (const float*)d_in[21];
    const float* w3  = (const float*)d_in[22];
    const float* b3  = (const float*)d_in[23];
    const float* g3  = (const float*)d_in[24];
    const float* be3 = (const float*)d_in[25];
    const float* m3  = (const float*)d_in[26];
    const float* v3  = (const float*)d_in[27];

    float* ws  = (float*)d_ws;
    float* bev = ws;                              // [4,2,1024,1024] f32 (ws+0 .. 8,388,608)
    float* x2  = ws + 8388608;                    // [4,16,256,256] f32 (.. 12,582,912)
    _Float16* x3h = (_Float16*)ws;                // [4,256,256,32] f16 (reuses bev, dead after conv12)
    _Float16* wh  = (_Float16*)(ws + 16777216);   // [9][64][32] f16 (dedicated region)
    float* tv  = ws + 16786432;                   // [64] f32
    float* outp = (float*)d_out;                  // [4,64,128,128] f32

    k_wprep<<<9, 256, 0, stream>>>(w3, b3, g3, be3, m3, v3, wh, tv);
    k_init_bev<<<32768, 256, 0, stream>>>(bev);
    k_rasterize<<<(n + 255)/256, 256, 0, stream>>>(points, bev, n);
    k_conv12<<<2048, 256, 0, stream>>>(bev, w0, b0, g0, be0, m0, v0,
                                       w1, b1, g1, be1, m1, v1, x2);
    k_dwpw<<<1024, 256, 0, stream>>>(x2, wdw, bdw, wpw, bpw, g2, be2, m2, v2, x3h);
    k_conv3m<<<512, 256, 0, stream>>>(x3h, wh, tv, outp);
}

// Round 9
// 146.984 us; speedup vs baseline: 1.2703x; 1.2703x over previous
//
#include <hip/hip_runtime.h>
#include <cstddef>

#define H_IN 1024
#define W_IN 1024
#define BN_EPS 1e-5f

typedef float f32x4 __attribute__((ext_vector_type(4)));
typedef _Float16 f16x8 __attribute__((ext_vector_type(8)));

__device__ __forceinline__ void atomicMaxF(float* addr, float val) {
    if (val >= 0.0f) {
        atomicMax((int*)addr, __float_as_int(val));
    } else {
        atomicMin((unsigned int*)addr, __float_as_uint(val));
    }
}

// ---------------- stage 0: BEV init + rasterize ----------------
__global__ void k_init_bev(float* __restrict__ bev) {
    size_t i = (size_t)blockIdx.x * blockDim.x + threadIdx.x;
    int plane = (int)((i >> 20) & 1);   // H*W = 2^20
    bev[i] = plane == 0 ? -10.0f : 0.0f;
}

__global__ void k_rasterize(const float* __restrict__ pts, float* __restrict__ bev, int n) {
    int i = blockIdx.x * blockDim.x + threadIdx.x;
    if (i >= n) return;
    float fb  = pts[(size_t)i*5+0];
    float px  = pts[(size_t)i*5+1];
    float py  = pts[(size_t)i*5+2];
    float pz  = pts[(size_t)i*5+3];
    float pit = pts[(size_t)i*5+4];
    const float XS = (float)(1024.0/69.12);
    const float YS = (float)(1024.0/79.36);
    int xp = (int)(px * XS);                  // trunc toward zero, same as astype(int32)
    int yp = (int)((py + 39.68f) * YS);
    if (xp < 0 || xp >= W_IN || yp < 0 || yp >= H_IN) return;
    int b = (int)fb;
    size_t off = (size_t)(b*2) * (H_IN*(size_t)W_IN) + (size_t)yp*W_IN + xp;
    atomicMaxF(bev + off, pz);
    atomicMaxF(bev + off + (size_t)H_IN*W_IN, pit);
}

// ---------------- stage 1: conv1(2->8,3x3,pad1)+BN+ReLU+maxpool2 -> f16 ----------------
// in:  bev [4,2,1024,1024] f32   out: x1h [4,8,512,512] f16
// naive per-thread form (r6-validated fastest); overlap reads are L1/L2-served.
__global__ __launch_bounds__(256, 4) void k_conv1(
                        const float* __restrict__ bev, const float* __restrict__ w0,
                        const float* __restrict__ b0, const float* __restrict__ g0,
                        const float* __restrict__ be0, const float* __restrict__ m0,
                        const float* __restrict__ v0, _Float16* __restrict__ out) {
    __shared__ float wS[144];       // [8][2][3][3]
    __shared__ float sS[8], tS[8];
    int t = threadIdx.x;
    if (t < 144) wS[t] = w0[t];
    if (t < 8) {
        float s = g0[t] / sqrtf(v0[t] + BN_EPS);
        sS[t] = s;
        tS[t] = (b0[t] - m0[t]) * s + be0[t];
    }
    __syncthreads();
    int idx = blockIdx.x * 256 + t;                 // 4*512*512 total
    int x = idx & 511, y = (idx >> 9) & 511, b = idx >> 18;
    const float* base = bev + (size_t)b * 2 * H_IN * W_IN;
    float in[2][4][4];
    #pragma unroll
    for (int c = 0; c < 2; c++)
        #pragma unroll
        for (int r = 0; r < 4; r++) {
            int iy = 2*y - 1 + r;
            #pragma unroll
            for (int cc = 0; cc < 4; cc++) {
                int ix = 2*x - 1 + cc;
                in[c][r][cc] = (iy >= 0 && iy < H_IN && ix >= 0 && ix < W_IN)
                    ? base[(size_t)c*H_IN*W_IN + (size_t)iy*W_IN + ix] : 0.0f;
            }
        }
    _Float16* ob = out + (size_t)b * 8 * 512 * 512 + (size_t)y*512 + x;
    #pragma unroll
    for (int oc = 0; oc < 8; oc++) {
        float mx = 0.0f;                            // post-ReLU values are >= 0
        #pragma unroll
        for (int py = 0; py < 2; py++)
            #pragma unroll
            for (int px = 0; px < 2; px++) {
                float acc = 0.0f;
                #pragma unroll
                for (int c = 0; c < 2; c++)
                    #pragma unroll
                    for (int kh = 0; kh < 3; kh++)
                        #pragma unroll
                        for (int kw = 0; kw < 3; kw++)
                            acc += in[c][py+kh][px+kw] * wS[((oc*2+c)*3+kh)*3+kw];
                acc = fmaxf(acc * sS[oc] + tS[oc], 0.0f);
                mx = fmaxf(mx, acc);
            }
        ob[(size_t)oc*512*512] = (_Float16)mx;
    }
}

// ---------------- stage 2: conv2 grouped(8)+BN+ReLU+maxpool2 ----------------
// in: x1h [4,8,512,512] f16   out: x2 [4,16,256,256] f32   (oc reads ic = oc>>1)
__global__ __launch_bounds__(256, 4) void k_conv2(
                        const _Float16* __restrict__ x1, const float* __restrict__ w1,
                        const float* __restrict__ b1, const float* __restrict__ g1,
                        const float* __restrict__ be1, const float* __restrict__ m1,
                        const float* __restrict__ v1, float* __restrict__ out) {
    __shared__ float wS[144];       // [16][3][3]
    __shared__ float sS[16], tS[16];
    int t = threadIdx.x;
    if (t < 144) wS[t] = w1[t];
    if (t < 16) {
        float s = g1[t] / sqrtf(v1[t] + BN_EPS);
        sS[t] = s;
        tS[t] = (b1[t] - m1[t]) * s + be1[t];
    }
    __syncthreads();
    int idx = blockIdx.x * 256 + t;                 // 4*256*256 total
    int x = idx & 255, y = (idx >> 8) & 255, b = idx >> 16;
    const _Float16* base = x1 + (size_t)b * 8 * 512 * 512;
    float* ob = out + (size_t)b * 16 * 256 * 256 + (size_t)y*256 + x;
    #pragma unroll
    for (int g = 0; g < 8; g++) {
        float p[4][4];
        #pragma unroll
        for (int r = 0; r < 4; r++) {
            int iy = 2*y - 1 + r;
            #pragma unroll
            for (int c = 0; c < 4; c++) {
                int ix = 2*x - 1 + c;
                p[r][c] = (iy >= 0 && iy < 512 && ix >= 0 && ix < 512)
                    ? (float)base[(size_t)g*512*512 + (size_t)iy*512 + ix] : 0.0f;
            }
        }
        #pragma unroll
        for (int sub = 0; sub < 2; sub++) {
            int oc = g*2 + sub;
            float mx = 0.0f;
            #pragma unroll
            for (int py = 0; py < 2; py++)
                #pragma unroll
                for (int px = 0; px < 2; px++) {
                    float acc = 0.0f;
                    #pragma unroll
                    for (int kh = 0; kh < 3; kh++)
                        #pragma unroll
                        for (int kw = 0; kw < 3; kw++)
                            acc += p[py+kh][px+kw] * wS[(oc*3+kh)*3+kw];
                    acc = fmaxf(acc * sS[oc] + tS[oc], 0.0f);
                    mx = fmaxf(mx, acc);
                }
            ob[(size_t)oc*65536] = mx;
        }
    }
}

// ---------------- stage 3: depthwise + pointwise + BN + ReLU -> f16 NHWC ----------------
// in: x2 [4,16,256,256] f32   out: x3h [4,256,256,32] f16  (LDS-tiled, r5-validated)
__global__ __launch_bounds__(256, 4) void k_dwpw(
                       const float* __restrict__ x2, const float* __restrict__ wdw,
                       const float* __restrict__ bdw, const float* __restrict__ wpw,
                       const float* __restrict__ bpw, const float* __restrict__ g2,
                       const float* __restrict__ be2, const float* __restrict__ m2,
                       const float* __restrict__ v2, _Float16* __restrict__ out) {
    __shared__ float patch[16*10*36];   // 23040 B
    __shared__ float wdwS[144];         // [16][3][3]
    __shared__ float bdwS[16];
    __shared__ float wpwS[512];         // [32][16]
    __shared__ float sS[32], tS[32];
    int t = threadIdx.x;
    if (t < 144) wdwS[t] = wdw[t];
    if (t < 16) bdwS[t] = bdw[t];
    for (int i = t; i < 512; i += 256) wpwS[i] = wpw[i];
    if (t < 32) {
        float s = g2[t] / sqrtf(v2[t] + BN_EPS);
        sS[t] = s;
        tS[t] = (bpw[t] - m2[t]) * s + be2[t];
    }

    int bi = blockIdx.x;                 // 1024 = 8 tx * 32 ty * 4 b
    int tx = bi & 7, ty = (bi >> 3) & 31, b = bi >> 8;
    int x0 = tx * 32, y0 = ty * 8;
    const float* base = x2 + (size_t)b * 16 * 256 * 256;

    for (int i = t; i < 16*10*34; i += 256) {
        int ic = i / 340;
        int rem = i - ic * 340;
        int r = rem / 34, c = rem - r * 34;
        int gy = y0 - 1 + r, gx = x0 - 1 + c;
        patch[(ic*10 + r)*36 + c] =
            (gy >= 0 && gy < 256 && gx >= 0 && gx < 256)
                ? base[(size_t)ic*65536 + (size_t)gy*256 + gx] : 0.0f;
    }
    __syncthreads();

    int px = t & 31, pyy = t >> 5;       // pixel within tile
    int x = x0 + px, y = y0 + pyy;

    float dv[16];
    #pragma unroll
    for (int ic = 0; ic < 16; ic++) {
        float d = bdwS[ic];
        #pragma unroll
        for (int r = 0; r < 3; r++)
            #pragma unroll
            for (int c = 0; c < 3; c++)
                d += patch[(ic*10 + pyy + r)*36 + px + c] * wdwS[ic*9 + r*3 + c];
        dv[ic] = d;
    }

    _Float16* ob = out + ((size_t)((b*256 + y)*256 + x)) * 32;
    #pragma unroll
    for (int q = 0; q < 4; q++) {
        f16x8 ov;
        #pragma unroll
        for (int j = 0; j < 8; j++) {
            int oc = q*8 + j;
            float a = 0.0f;
            #pragma unroll
            for (int ic = 0; ic < 16; ic++)
                a += dv[ic] * wpwS[oc*16+ic];
            ov[j] = (_Float16)fmaxf(a*sS[oc] + tS[oc], 0.0f);
        }
        *(f16x8*)(ob + q*8) = ov;
    }
}

// ---------------- weight prep for conv3 MFMA (9 blocks, one per tap) ----------------
__global__ void k_wprep(const float* __restrict__ w3, const float* __restrict__ b3,
                        const float* __restrict__ g3, const float* __restrict__ be3,
                        const float* __restrict__ m3, const float* __restrict__ v3,
                        _Float16* __restrict__ wh, float* __restrict__ tv) {
    __shared__ float sSh[64];
    int t = threadIdx.x;
    if (t < 64) {
        float s = g3[t] / sqrtf(v3[t] + BN_EPS);
        sSh[t] = s;
        if (blockIdx.x == 0) tv[t] = (b3[t] - m3[t]) * s + be3[t];
    }
    __syncthreads();
    int khw = blockIdx.x;
    for (int i = t; i < 2048; i += 256) {
        int oc = i >> 5;                       // i = oc*32 + ic
        wh[khw*2048 + i] = (_Float16)(w3[(size_t)i*9 + khw] * sSh[oc]);
    }
}

// ---------------- stage 4: conv3 via MFMA f16 implicit GEMM + BN + ReLU + maxpool2 ----------------
// in: x3h [4,256,256,32] f16 NHWC, wh [9][64][32] f16, tv[64] f32
// out: d_out [4,64,128,128] f32
// r8-validated: stage 10 rows ONCE per block (52.8 KB LDS), 1 barrier, 4 row-tiles.
__global__ __launch_bounds__(256, 2) void k_conv3m(const _Float16* __restrict__ xh,
                                                   const _Float16* __restrict__ wh,
                                                   const float* __restrict__ tv,
                                                   float* __restrict__ out) {
    __shared__ _Float16 As[10*66*40];       // rows x px x ic(pad 32->40), 52800 B
    int t = threadIdx.x;
    int lane = t & 63, w = t >> 6;
    int l15 = lane & 15, l4 = lane >> 4;
    int bi = blockIdx.x;
    int xt = bi & 3, yg = (bi >> 2) & 31, b = bi >> 7;
    int x0 = xt * 64;
    int y0 = yg * 8;                        // pre-pool row base (256-grid)

    f16x8 Bf[9][4];
    #pragma unroll
    for (int khw = 0; khw < 9; khw++)
        #pragma unroll
        for (int g = 0; g < 4; g++)
            Bf[khw][g] = *(const f16x8*)(wh + ((khw*64 + g*16 + l15)*32 + 8*l4));

    float tvv[4];
    #pragma unroll
    for (int g = 0; g < 4; g++) tvv[g] = tv[g*16 + l15];

    for (int s = t; s < 660; s += 256) {
        int row = s / 66, px = s - row*66;
        int gy = y0 - 1 + row, gx = x0 - 1 + px;
        float4* dst = (float4*)&As[(row*66 + px)*40];
        if (gy >= 0 && gy < 256 && gx >= 0 && gx < 256) {
            const float4* src = (const float4*)(xh + ((size_t)((b*256 + gy)*256 + gx)) * 32);
            #pragma unroll
            for (int j = 0; j < 4; j++) dst[j] = src[j];
        } else {
            float4 z = make_float4(0.f, 0.f, 0.f, 0.f);
            #pragma unroll
            for (int j = 0; j < 4; j++) dst[j] = z;
        }
    }
    __syncthreads();

    for (int ti = 0; ti < 4; ti++) {
        int ypool = yg*4 + ti;              // pooled row 0..127
        f32x4 acc[2][4];
        #pragma unroll
        for (int f = 0; f < 2; f++)
            #pragma unroll
            for (int g = 0; g < 4; g++)
                acc[f][g] = (f32x4){0.f, 0.f, 0.f, 0.f};

        #pragma unroll
        for (int kh = 0; kh < 3; kh++)
            #pragma unroll
            for (int kw = 0; kw < 3; kw++) {
                f16x8 Af[2];
                #pragma unroll
                for (int f = 0; f < 2; f++) {
                    int row = 2*ti + f + kh;                // staged row idx
                    int px = w*16 + l15 + kw;               // staged px idx
                    Af[f] = *(const f16x8*)&As[(row*66 + px)*40 + 8*l4];
                }
                #pragma unroll
                for (int f = 0; f < 2; f++)
                    #pragma unroll
                    for (int g = 0; g < 4; g++)
                        acc[f][g] = __builtin_amdgcn_mfma_f32_16x16x32_f16(
                            Af[f], Bf[kh*3+kw][g], acc[f][g], 0, 0, 0);
            }

        #pragma unroll
        for (int g = 0; g < 4; g++) {
            int oc = g*16 + l15;
            #pragma unroll
            for (int q = 0; q < 2; q++) {
                float v0 = fmaxf(fmaxf(acc[0][g][2*q]   + tvv[g], 0.f),
                                 fmaxf(acc[0][g][2*q+1] + tvv[g], 0.f));
                float v1 = fmaxf(fmaxf(acc[1][g][2*q]   + tvv[g], 0.f),
                                 fmaxf(acc[1][g][2*q+1] + tvv[g], 0.f));
                int px = x0/2 + w*8 + 2*l4 + q;
                out[(((size_t)b*64 + oc)*128 + ypool)*128 + px] = fmaxf(v0, v1);
            }
        }
    }
}

extern "C" void kernel_launch(void* const* d_in, const int* in_sizes, int n_in,
                              void* d_out, int out_size, void* d_ws, size_t ws_size,
                              hipStream_t stream) {
    const float* points = (const float*)d_in[0];
    int n = in_sizes[0] / 5;
    const float* w0  = (const float*)d_in[2];
    const float* b0  = (const float*)d_in[3];
    const float* g0  = (const float*)d_in[4];
    const float* be0 = (const float*)d_in[5];
    const float* m0  = (const float*)d_in[6];
    const float* v0  = (const float*)d_in[7];
    const float* w1  = (const float*)d_in[8];
    const float* b1  = (const float*)d_in[9];
    const float* g1  = (const float*)d_in[10];
    const float* be1 = (const float*)d_in[11];
    const float* m1  = (const float*)d_in[12];
    const float* v1  = (const float*)d_in[13];
    const float* wdw = (const float*)d_in[14];
    const float* bdw = (const float*)d_in[15];
    const float* wpw = (const float*)d_in[16];
    const float* bpw = (const float*)d_in[17];
    const float* g2  = (const float*)d_in[18];
    const float* be2 = (const float*)d_in[19];
    const float* m2  = (const float*)d_in[20];
    const float* v2  = (const float*)d_in[21];
    const float* w3  = (const float*)d_in[22];
    const float* b3  = (const float*)d_in[23];
    const float* g3  = (const float*)d_in[24];
    const float* be3 = (const float*)d_in[25];
    const float* m3  = (const float*)d_in[26];
    const float* v3  = (const float*)d_in[27];

    float* ws  = (float*)d_ws;
    // layout (float indices into ws):
    //   bev  [4,2,1024,1024] f32 : 0 .. 8,388,608        (dead after conv1)
    //   x1h  [4,8,512,512]   f16 : 8,388,608 .. 12,582,912 (dead after conv2)
    //   x2   [4,16,256,256]  f32 : 0 .. 4,194,304        (reuses bev; dead after dwpw)
    //   x3h  [4,256,256,32]  f16 : 8,388,608 .. 12,582,912 (reuses x1h; dead after conv3m)
    //   wh   [9][64][32]     f16 : 16,777,216 ..          (dedicated, never aliased)
    float* bev = ws;
    _Float16* x1h = (_Float16*)(ws + 8388608);
    float* x2  = ws;
    _Float16* x3h = (_Float16*)(ws + 8388608);
    _Float16* wh  = (_Float16*)(ws + 16777216);
    float* tv  = ws + 16786432;
    float* outp = (float*)d_out;

    k_wprep<<<9, 256, 0, stream>>>(w3, b3, g3, be3, m3, v3, wh, tv);
    k_init_bev<<<32768, 256, 0, stream>>>(bev);
    k_rasterize<<<(n + 255)/256, 256, 0, stream>>>(points, bev, n);
    k_conv1<<<4096, 256, 0, stream>>>(bev, w0, b0, g0, be0, m0, v0, x1h);
    k_conv2<<<1024, 256, 0, stream>>>(x1h, w1, b1, g1, be1, m1, v1, x2);
    k_dwpw<<<1024, 256, 0, stream>>>(x2, wdw, bdw, wpw, bpw, g2, be2, m2, v2, x3h);
    k_conv3m<<<512, 256, 0, stream>>>(x3h, wh, tv, outp);
}